// Round 12
// baseline (208.887 us; speedup 1.0000x reference)
//
#include <hip/hip_runtime.h>
#include <math.h>

#define BDIM 8
#define IMG 224
#define PP 16
#define GG 14
#define NN 196
#define PD 256
#define DD 128
#define DFFV 256
#define CC 1000
#define ROWS 7

#define NEGINF (-INFINITY)

// monotonic float<->uint order-preserving encoding for atomicMax pooling
__device__ __forceinline__ unsigned keyenc(float f) {
  unsigned u = __float_as_uint(f);
  return (u & 0x80000000u) ? ~u : (u | 0x80000000u);
}
__device__ __forceinline__ float keydec(unsigned k) {
  unsigned u = (k & 0x80000000u) ? (k & 0x7fffffffu) : ~k;
  return __uint_as_float(u);
}

// ========== K1: embed + qkv(L0). grid (28, B), 448 threads, 7 rows ========
__global__ __launch_bounds__(448) void embed_qkv_kernel(
    const float* __restrict__ x, const float* __restrict__ eW,
    const float* __restrict__ pos, const float* __restrict__ qW,
    const float* __restrict__ kW, const float* __restrict__ vW,
    float* __restrict__ h, float* __restrict__ qg, float* __restrict__ kg,
    float* __restrict__ vg, unsigned* __restrict__ poolkey) {
  int nt = blockIdx.x, b = blockIdx.y, n0 = nt * ROWS;
  __shared__ float patch[ROWS][PD];  // 7 KB
  __shared__ float hrow[ROWS][DD];   // 3.5 KB
  __shared__ float mxs[ROWS];
  int t = threadIdx.x;
  if (nt == 0 && t < DD) poolkey[b * DD + t] = 0u;
  // stage 7 patches: 448 float4, one per thread
  {
    int p = t >> 6, r = t & 63, pi = r >> 2, pj4 = r & 3;
    int n = n0 + p, gi = n / GG, gj = n % GG;
    float4 val = *reinterpret_cast<const float4*>(
        x + (size_t)(b * IMG + gi * PP + pi) * IMG + gj * PP + pj4 * 4);
    *reinterpret_cast<float4*>(&patch[p][pi * PP + pj4 * 4]) = val;
  }
  __syncthreads();
  // embed: 896 (row,d) outputs, 2 per thread
  for (int o = t; o < ROWS * DD; o += 448) {
    int p = o >> 7, d = o & 127;
    const float4* W4 = reinterpret_cast<const float4*>(eW + (size_t)d * PD);
    const float4* P4 = reinterpret_cast<const float4*>(&patch[p][0]);
    float a = NEGINF;
#pragma unroll 4
    for (int j4 = 0; j4 < PD / 4; j4++) {
      float4 w = W4[j4], pp = P4[j4];
      a = fmaxf(a, pp.x + w.x); a = fmaxf(a, pp.y + w.y);
      a = fmaxf(a, pp.z + w.z); a = fmaxf(a, pp.w + w.w);
    }
    float hv = a + pos[(size_t)(n0 + p) * DD + d];
    hrow[p][d] = hv;
    h[(size_t)(b * NN + n0 + p) * DD + d] = hv;
  }
  __syncthreads();
  // rowmax (pnorm constants): 7 groups of 32 lanes
  if (t < ROWS * 32) {
    int r = t >> 5, l = t & 31;
    float m = fmaxf(fmaxf(hrow[r][l], hrow[r][l + 32]),
                    fmaxf(hrow[r][l + 64], hrow[r][l + 96]));
#pragma unroll
    for (int mask = 16; mask >= 1; mask >>= 1) m = fmaxf(m, __shfl_xor(m, mask));
    if (l == 0) mxs[r] = m;
  }
  __syncthreads();
  // qkv: thread group m in {0,1,2} -> q/k/v, i = output dim; 7 rows each
  if (t < 3 * DD) {
    int m = t >> 7, i = t & 127;
    const float* W = (m == 0) ? qW : (m == 1 ? kW : vW);
    const float4* W4 = reinterpret_cast<const float4*>(W + (size_t)i * DD);
    float acc[ROWS];
#pragma unroll
    for (int r = 0; r < ROWS; r++) acc[r] = NEGINF;
#pragma unroll 4
    for (int j4 = 0; j4 < DD / 4; j4++) {
      float4 w = W4[j4];
#pragma unroll
      for (int r = 0; r < ROWS; r++) {
        float4 xv = *reinterpret_cast<const float4*>(&hrow[r][j4 * 4]);
        acc[r] = fmaxf(acc[r], xv.x + w.x); acc[r] = fmaxf(acc[r], xv.y + w.y);
        acc[r] = fmaxf(acc[r], xv.z + w.z); acc[r] = fmaxf(acc[r], xv.w + w.w);
      }
    }
    float* dst = (m == 0) ? qg : (m == 1 ? kg : vg);
#pragma unroll
    for (int r = 0; r < ROWS; r++)
      dst[(size_t)(b * NN + n0 + r) * DD + i] = acc[r] - mxs[r];
  }
}

// ==== K2/K3: attn + ffn1 + ffn2 (+ next qkv | pool). grid (28,B), 448 ====
__global__ __launch_bounds__(448) void layer_kernel(
    const float* __restrict__ qg, const float* __restrict__ kg,
    const float* __restrict__ vg, float* __restrict__ h,
    const float* __restrict__ f1W, const float* __restrict__ f2W,
    const float* __restrict__ tau, const float* __restrict__ qWn,
    const float* __restrict__ kWn, const float* __restrict__ vWn,
    float* __restrict__ qo, float* __restrict__ ko, float* __restrict__ vo,
    unsigned* __restrict__ poolkey) {
  int nt = blockIdx.x, b = blockIdx.y, i0 = nt * ROWS;
  __shared__ float qs[ROWS][DD];          // 3.5 KB
  __shared__ float hrow[ROWS][DD];        // 3.5 KB
  __shared__ float sc[ROWS][NN];          // 5.4 KB
  __shared__ float h1s[ROWS][DFFV];       // 7 KB
  __shared__ float scratch[14 * ROWS * DD];  // 49 KB (PV partials / ffn2 alias)
  __shared__ float red[2][ROWS];
  __shared__ float mxs[ROWS];
  int t = threadIdx.x;
  // ---- stage qs and hrow (own 7 rows): 224 float4 each ----
  if (t < 224) {
    float4 val = reinterpret_cast<const float4*>(qg + (size_t)(b * NN + i0) * DD)[t];
    *reinterpret_cast<float4*>(&qs[0][0] + t * 4) = val;
  } else {
    int tt = t - 224;
    float4 val = reinterpret_cast<const float4*>(h + (size_t)(b * NN + i0) * DD)[tt];
    *reinterpret_cast<float4*>(&hrow[0][0] + tt * 4) = val;
  }
  __syncthreads();
  // ---- scores: thread t = key index j, 7 q-rows ----
  if (t < NN) {
    const float4* k4 = reinterpret_cast<const float4*>(kg + (size_t)(b * NN + t) * DD);
    float s[ROWS];
#pragma unroll
    for (int r = 0; r < ROWS; r++) s[r] = NEGINF;
#pragma unroll 4
    for (int d4 = 0; d4 < DD / 4; d4++) {
      float4 kv = k4[d4];
#pragma unroll
      for (int r = 0; r < ROWS; r++) {
        float4 qv = *reinterpret_cast<const float4*>(&qs[r][d4 * 4]);
        s[r] = fmaxf(s[r], qv.x + kv.x); s[r] = fmaxf(s[r], qv.y + kv.y);
        s[r] = fmaxf(s[r], qv.z + kv.z); s[r] = fmaxf(s[r], qv.w + kv.w);
      }
    }
#pragma unroll
    for (int r = 0; r < ROWS; r++) sc[r][t] = s[r];
  }
  __syncthreads();
  // ---- PV: 14 j-groups x 32 d4-slots; 196 = 14 x 14 iters ----
  {
    int d4 = t & 31, jg = t >> 5;  // jg in [0,14)
    float4 o[ROWS];
#pragma unroll
    for (int r = 0; r < ROWS; r++) o[r] = make_float4(NEGINF, NEGINF, NEGINF, NEGINF);
    for (int j = jg; j < NN; j += 14) {
      float4 vv = *reinterpret_cast<const float4*>(vg + (size_t)(b * NN + j) * DD + d4 * 4);
#pragma unroll
      for (int r = 0; r < ROWS; r++) {
        float c = sc[r][j];
        o[r].x = fmaxf(o[r].x, c + vv.x); o[r].y = fmaxf(o[r].y, c + vv.y);
        o[r].z = fmaxf(o[r].z, c + vv.z); o[r].w = fmaxf(o[r].w, c + vv.w);
      }
    }
#pragma unroll
    for (int r = 0; r < ROWS; r++)
      *reinterpret_cast<float4*>(&scratch[((jg * ROWS + r) << 7) + d4 * 4]) = o[r];
  }
  __syncthreads();
  // ---- combine 14 PV partials; pnorm max per row ----
  float oacc[ROWS];
  if (t < 128) {
    int lane = t & 63, wv = t >> 6;
#pragma unroll
    for (int r = 0; r < ROWS; r++) {
      float m = scratch[(r << 7) + t];
#pragma unroll
      for (int g = 1; g < 14; g++) m = fmaxf(m, scratch[((g * ROWS + r) << 7) + t]);
      oacc[r] = m;
      float mv = m;
#pragma unroll
      for (int mask = 32; mask >= 1; mask >>= 1) mv = fmaxf(mv, __shfl_xor(mv, mask));
      if (lane == 0) red[wv][r] = mv;
    }
  }
  __syncthreads();
  // ---- attn pnorm + tropical residual into hrow ----
  if (t < 128) {
#pragma unroll
    for (int r = 0; r < ROWS; r++) {
      float omax = fmaxf(red[0][r], red[1][r]);
      hrow[r][t] = fmaxf(hrow[r][t], oacc[r] - omax);
    }
  }
  __syncthreads();
  // ---- ffn1 rowmax: 7 groups of 32 lanes ----
  if (t < ROWS * 32) {
    int r = t >> 5, l = t & 31;
    float m = fmaxf(fmaxf(hrow[r][l], hrow[r][l + 32]),
                    fmaxf(hrow[r][l + 64], hrow[r][l + 96]));
#pragma unroll
    for (int mask = 16; mask >= 1; mask >>= 1) m = fmaxf(m, __shfl_xor(m, mask));
    if (l == 0) mxs[r] = m;
  }
  __syncthreads();
  // ---- ffn1: t<256, one output each, 7 rows ----
  if (t < DFFV) {
    float tv = tau[0];
    const float4* W4 = reinterpret_cast<const float4*>(f1W + (size_t)t * DD);
    float acc[ROWS];
#pragma unroll
    for (int r = 0; r < ROWS; r++) acc[r] = NEGINF;
#pragma unroll 4
    for (int j4 = 0; j4 < DD / 4; j4++) {
      float4 w = W4[j4];
#pragma unroll
      for (int r = 0; r < ROWS; r++) {
        float4 xv = *reinterpret_cast<const float4*>(&hrow[r][j4 * 4]);
        acc[r] = fmaxf(acc[r], xv.x + w.x); acc[r] = fmaxf(acc[r], xv.y + w.y);
        acc[r] = fmaxf(acc[r], xv.z + w.z); acc[r] = fmaxf(acc[r], xv.w + w.w);
      }
    }
#pragma unroll
    for (int r = 0; r < ROWS; r++) h1s[r][t] = fmaxf(acc[r] - mxs[r], tv);
  }
  __syncthreads();
  // ---- ffn2: t<256, (i = t&127, jh = t>>7) half-reduce, 7 rows ----
  if (t < DFFV) {
    int i = t & 127, jh = t >> 7;
    const float4* W4 = reinterpret_cast<const float4*>(f2W + (size_t)i * DFFV) + jh * 32;
    float acc[ROWS];
#pragma unroll
    for (int r = 0; r < ROWS; r++) acc[r] = NEGINF;
#pragma unroll 4
    for (int j4 = 0; j4 < 32; j4++) {
      float4 w = W4[j4];
#pragma unroll
      for (int r = 0; r < ROWS; r++) {
        float4 y = *reinterpret_cast<const float4*>(&h1s[r][jh * 128 + j4 * 4]);
        acc[r] = fmaxf(acc[r], y.x + w.x); acc[r] = fmaxf(acc[r], y.y + w.y);
        acc[r] = fmaxf(acc[r], y.z + w.z); acc[r] = fmaxf(acc[r], y.w + w.w);
      }
    }
#pragma unroll
    for (int r = 0; r < ROWS; r++) scratch[((jh * ROWS + r) << 7) + i] = acc[r];
  }
  __syncthreads();
  float fm[ROWS];
  if (t < 128) {
    int lane = t & 63, wv = t >> 6;
#pragma unroll
    for (int r = 0; r < ROWS; r++) {
      fm[r] = fmaxf(scratch[(r << 7) + t], scratch[((ROWS + r) << 7) + t]);
      float mv = fm[r];
#pragma unroll
      for (int mask = 32; mask >= 1; mask >>= 1) mv = fmaxf(mv, __shfl_xor(mv, mask));
      if (lane == 0) red[wv][r] = mv;
    }
  }
  __syncthreads();
  if (qWn == nullptr) {
    // final layer: fused global pooling over this block's 7 rows
    if (t < 128) {
      float pool = NEGINF;
#pragma unroll
      for (int r = 0; r < ROWS; r++) {
        float omax = fmaxf(red[0][r], red[1][r]);
        pool = fmaxf(pool, fmaxf(hrow[r][t], fm[r] - omax));
      }
      atomicMax(&poolkey[b * DD + t], keyenc(pool));
    }
    return;
  }
  // ---- ffn pnorm + residual; h hand-off; rowmax for next qkv ----
  if (t < 128) {
    int lane = t & 63, wv = t >> 6;
#pragma unroll
    for (int r = 0; r < ROWS; r++) {
      float omax = fmaxf(red[0][r], red[1][r]);
      float nh = fmaxf(hrow[r][t], fm[r] - omax);
      hrow[r][t] = nh;
      h[(size_t)(b * NN + i0 + r) * DD + t] = nh;
      float mv = nh;
#pragma unroll
      for (int mask = 32; mask >= 1; mask >>= 1) mv = fmaxf(mv, __shfl_xor(mv, mask));
      if (lane == 0) red[wv][r] = mv;
    }
  }
  __syncthreads();
  // ---- next-layer qkv: t<384, 3 groups x 128 dims x 7 rows ----
  if (t < 3 * DD) {
    int m = t >> 7, i = t & 127;
    const float* W = (m == 0) ? qWn : (m == 1 ? kWn : vWn);
    const float4* W4 = reinterpret_cast<const float4*>(W + (size_t)i * DD);
    float acc[ROWS], mx[ROWS];
#pragma unroll
    for (int r = 0; r < ROWS; r++) {
      acc[r] = NEGINF;
      mx[r] = fmaxf(red[0][r], red[1][r]);
    }
#pragma unroll 4
    for (int j4 = 0; j4 < DD / 4; j4++) {
      float4 w = W4[j4];
#pragma unroll
      for (int r = 0; r < ROWS; r++) {
        float4 xv = *reinterpret_cast<const float4*>(&hrow[r][j4 * 4]);
        acc[r] = fmaxf(acc[r], xv.x + w.x); acc[r] = fmaxf(acc[r], xv.y + w.y);
        acc[r] = fmaxf(acc[r], xv.z + w.z); acc[r] = fmaxf(acc[r], xv.w + w.w);
      }
    }
    float* dst = (m == 0) ? qo : (m == 1 ? ko : vo);
#pragma unroll
    for (int r = 0; r < ROWS; r++)
      dst[(size_t)(b * NN + i0 + r) * DD + i] = acc[r] - mx[r];
  }
}

// ============ K4: head from pooled keys. grid (8, B), 128 threads =========
__global__ __launch_bounds__(128) void head_kernel(
    const unsigned* __restrict__ poolkey, const float* __restrict__ hW,
    const float* __restrict__ lscale, float* __restrict__ out) {
  int cb = blockIdx.x, b = blockIdx.y;
  __shared__ float pooled[DD];
  int t = threadIdx.x;
  pooled[t] = keydec(poolkey[b * DD + t]);
  __syncthreads();
  if (t < 125) {
    int c = cb * 125 + t;
    const float4* W4 = reinterpret_cast<const float4*>(hW + (size_t)c * DD);
    float acc = NEGINF;
#pragma unroll 4
    for (int k4 = 0; k4 < DD / 4; k4++) {
      float4 w = W4[k4];
      float4 p = *reinterpret_cast<const float4*>(&pooled[k4 * 4]);
      acc = fmaxf(acc, p.x + w.x); acc = fmaxf(acc, p.y + w.y);
      acc = fmaxf(acc, p.z + w.z); acc = fmaxf(acc, p.w + w.w);
    }
    out[(size_t)b * CC + c] = acc * lscale[0];
  }
}

extern "C" void kernel_launch(void* const* d_in, const int* in_sizes, int n_in,
                              void* d_out, int out_size, void* d_ws, size_t ws_size,
                              hipStream_t stream) {
  const float* x = (const float*)d_in[0];
  const float* embed_W = (const float*)d_in[1];
  const float* pos = (const float*)d_in[2];
  const float* qW[2] = {(const float*)d_in[3], (const float*)d_in[9]};
  const float* kW[2] = {(const float*)d_in[4], (const float*)d_in[10]};
  const float* vW[2] = {(const float*)d_in[5], (const float*)d_in[11]};
  const float* f1W[2] = {(const float*)d_in[6], (const float*)d_in[12]};
  const float* f2W[2] = {(const float*)d_in[7], (const float*)d_in[13]};
  const float* tau[2] = {(const float*)d_in[8], (const float*)d_in[14]};
  const float* headW = (const float*)d_in[15];
  const float* lscale = (const float*)d_in[16];
  float* out = (float*)d_out;

  float* ws = (float*)d_ws;
  size_t o = 0;
  float* h = ws + o; o += (size_t)BDIM * NN * DD;
  float* qb = ws + o; o += (size_t)BDIM * NN * DD;
  float* kb = ws + o; o += (size_t)BDIM * NN * DD;
  float* vb = ws + o; o += (size_t)BDIM * NN * DD;
  float* k2 = ws + o; o += (size_t)BDIM * NN * DD;
  float* v2 = ws + o; o += (size_t)BDIM * NN * DD;
  unsigned* poolkey = (unsigned*)(ws + o); o += (size_t)BDIM * DD;

  // K1: embed + qkv(L0); also inits poolkey. 224 blocks -> <=1 block/CU.
  embed_qkv_kernel<<<dim3(28, BDIM), 448, 0, stream>>>(
      x, embed_W, pos, qW[0], kW[0], vW[0], h, qb, kb, vb, poolkey);
  // K2: attn(L0)+ffn(L0)+qkv(L1); q overwritten in place, k/v double-buffered
  layer_kernel<<<dim3(28, BDIM), 448, 0, stream>>>(
      qb, kb, vb, h, f1W[0], f2W[0], tau[0], qW[1], kW[1], vW[1], qb, k2, v2,
      poolkey);
  // K3: attn(L1)+ffn(L1) + fused global pooling via atomicMax keys
  layer_kernel<<<dim3(28, BDIM), 448, 0, stream>>>(
      qb, k2, v2, h, f1W[1], f2W[1], tau[1], nullptr, nullptr, nullptr,
      nullptr, nullptr, nullptr, poolkey);
  // K4: head from pooled
  head_kernel<<<dim3(8, BDIM), 128, 0, stream>>>(poolkey, headW, lscale, out);
}

// Round 13
// 153.904 us; speedup vs baseline: 1.3573x; 1.3573x over previous
//
#include <hip/hip_runtime.h>
#include <math.h>

#define BDIM 8
#define IMG 224
#define PP 16
#define GG 14
#define NN 196
#define PD 256
#define DD 128
#define DFFV 256
#define CC 1000

#define NEGINF (-INFINITY)

// wt buffer float4 offsets (transposed-weight arena)
#define WT4_EW    0        // [64][128]  eW
#define WT4_QKV0  8192     // [32][128] x3 (q,k,v layer0)
#define WT4_QKV1  20480    // [32][128] x3 (layer1)
#define WT4_F1_0  32768    // [32][256]
#define WT4_F1_1  40960
#define WT4_F2_0  49152    // [64][128]
#define WT4_F2_1  57344
#define WT4_HW    65536    // [32][1000]
#define WT4_TOTAL 97536
#define WT_FLOATS (WT4_TOTAL * 4)

// monotonic float<->uint order-preserving encoding for atomicMax pooling
__device__ __forceinline__ unsigned keyenc(float f) {
  unsigned u = __float_as_uint(f);
  return (u & 0x80000000u) ? ~u : (u | 0x80000000u);
}
__device__ __forceinline__ float keydec(unsigned k) {
  unsigned u = (k & 0x80000000u) ? (k & 0x7fffffffu) : ~k;
  return __uint_as_float(u);
}

// ===== K0: transpose all weights into [j4][out] float4 layout ============
// dst[local = j4*OUT + o] = src row o, floats [4j4 .. 4j4+3]. Coalesced write.
__global__ __launch_bounds__(256) void transpose_weights_kernel(
    const float* __restrict__ eW, const float* __restrict__ qW0,
    const float* __restrict__ kW0, const float* __restrict__ vW0,
    const float* __restrict__ qW1, const float* __restrict__ kW1,
    const float* __restrict__ vW1, const float* __restrict__ f1W0,
    const float* __restrict__ f1W1, const float* __restrict__ f2W0,
    const float* __restrict__ f2W1, const float* __restrict__ hW,
    float* __restrict__ wt) {
  int idx = blockIdx.x * 256 + threadIdx.x;
  float4* wt4 = reinterpret_cast<float4*>(wt);
  const float* src;
  float4* dst;
  int local, OUT, J;
  if (idx < 8192) {
    src = eW; dst = wt4 + WT4_EW; local = idx; OUT = 128; J = 256;
  } else if (idx < 32768) {
    int s = (idx - 8192) >> 12; local = (idx - 8192) & 4095;
    src = (s == 0) ? qW0 : (s == 1) ? kW0 : (s == 2) ? vW0
        : (s == 3) ? qW1 : (s == 4) ? kW1 : vW1;
    dst = wt4 + WT4_QKV0 + s * 4096; OUT = 128; J = 128;
  } else if (idx < 49152) {
    int s = (idx - 32768) >> 13; local = (idx - 32768) & 8191;
    src = s ? f1W1 : f1W0; dst = wt4 + WT4_F1_0 + s * 8192; OUT = 256; J = 128;
  } else if (idx < 65536) {
    int s = (idx - 49152) >> 13; local = (idx - 49152) & 8191;
    src = s ? f2W1 : f2W0; dst = wt4 + WT4_F2_0 + s * 8192; OUT = 128; J = 256;
  } else if (idx < WT4_TOTAL) {
    src = hW; dst = wt4 + WT4_HW; local = idx - 65536; OUT = 1000; J = 128;
  } else {
    return;
  }
  int o, j4;
  if (OUT == 128) { o = local & 127; j4 = local >> 7; }
  else if (OUT == 256) { o = local & 255; j4 = local >> 8; }
  else { o = local % 1000; j4 = local / 1000; }
  dst[local] = *reinterpret_cast<const float4*>(src + (size_t)o * J + j4 * 4);
}

// ===== K1: embed + qkv(L0). grid (49,B), 384 threads, 4 rows/block =======
// All weight reads coalesced via wt; K written transposed (KT[b][d4][j][4]).
__global__ __launch_bounds__(384) void embed_qkv_kernel(
    const float* __restrict__ x, const float* __restrict__ wt,
    const float* __restrict__ pos, float* __restrict__ h,
    float* __restrict__ qg, float* __restrict__ KT, float* __restrict__ vg,
    unsigned* __restrict__ poolkey) {
  int nt = blockIdx.x, b = blockIdx.y, n0 = nt * 4;
  __shared__ float patch[4][PD];  // 4 KB
  __shared__ float hrow[4][DD];   // 2 KB
  __shared__ float mxs[4];
  int t = threadIdx.x;
  const float4* wt4 = reinterpret_cast<const float4*>(wt);
  if (nt == 0 && t < DD) poolkey[b * DD + t] = 0u;
  // stage 4 patches (one per row), 256 float4 loads
  if (t < 256) {
    int p = t >> 6, r = t & 63, pi = r >> 2, pj4 = r & 3;
    int n = n0 + p, gi = n / GG, gj = n % GG;
    float4 val = *reinterpret_cast<const float4*>(
        x + (size_t)(b * IMG + gi * PP + pi) * IMG + gj * PP + pj4 * 4);
    *reinterpret_cast<float4*>(&patch[p][pi * PP + pj4 * 4]) = val;
  }
  __syncthreads();
  // embed: threads 0..255, each handles 2 rows for its d; eWT coalesced
  if (t < 256) {
    int half = t >> 7, d = t & 127;
    int p0 = half * 2, p1 = p0 + 1;
    float a0 = NEGINF, a1 = NEGINF;
    const float4* W4 = wt4 + WT4_EW;  // [j4][d]
#pragma unroll 4
    for (int j4 = 0; j4 < PD / 4; j4++) {
      float4 w = W4[j4 * DD + d];
      a0 = fmaxf(a0, patch[p0][j4 * 4 + 0] + w.x); a0 = fmaxf(a0, patch[p0][j4 * 4 + 1] + w.y);
      a0 = fmaxf(a0, patch[p0][j4 * 4 + 2] + w.z); a0 = fmaxf(a0, patch[p0][j4 * 4 + 3] + w.w);
      a1 = fmaxf(a1, patch[p1][j4 * 4 + 0] + w.x); a1 = fmaxf(a1, patch[p1][j4 * 4 + 1] + w.y);
      a1 = fmaxf(a1, patch[p1][j4 * 4 + 2] + w.z); a1 = fmaxf(a1, patch[p1][j4 * 4 + 3] + w.w);
    }
    float h0 = a0 + pos[(size_t)(n0 + p0) * DD + d];
    float h1v = a1 + pos[(size_t)(n0 + p1) * DD + d];
    hrow[p0][d] = h0; hrow[p1][d] = h1v;
    h[(size_t)(b * NN + n0 + p0) * DD + d] = h0;
    h[(size_t)(b * NN + n0 + p1) * DD + d] = h1v;
  }
  __syncthreads();
  // rowmax (pnorm constant) per row
  if (t < 128) {
    int r = t >> 5, l = t & 31;
    float m = fmaxf(fmaxf(hrow[r][l], hrow[r][l + 32]), fmaxf(hrow[r][l + 64], hrow[r][l + 96]));
#pragma unroll
    for (int mask = 16; mask >= 1; mask >>= 1) m = fmaxf(m, __shfl_xor(m, mask));
    if (l == 0) mxs[r] = m;
  }
  __syncthreads();
  // qkv: m in {0,1,2} -> q/k/v; coalesced WT reads; k written transposed
  {
    int m = t >> 7, i = t & 127;
    const float4* W4 = wt4 + WT4_QKV0 + m * 4096;  // [j4][i]
    float acc[4];
#pragma unroll
    for (int r = 0; r < 4; r++) acc[r] = NEGINF;
#pragma unroll 4
    for (int j4 = 0; j4 < DD / 4; j4++) {
      float4 w = W4[j4 * DD + i];
#pragma unroll
      for (int r = 0; r < 4; r++) {
        acc[r] = fmaxf(acc[r], hrow[r][j4 * 4 + 0] + w.x);
        acc[r] = fmaxf(acc[r], hrow[r][j4 * 4 + 1] + w.y);
        acc[r] = fmaxf(acc[r], hrow[r][j4 * 4 + 2] + w.z);
        acc[r] = fmaxf(acc[r], hrow[r][j4 * 4 + 3] + w.w);
      }
    }
    if (m == 0) {
#pragma unroll
      for (int r = 0; r < 4; r++)
        qg[(size_t)(b * NN + n0 + r) * DD + i] = acc[r] - mxs[r];
    } else if (m == 1) {
#pragma unroll
      for (int r = 0; r < 4; r++)
        KT[(((size_t)b * 32 + (i >> 2)) * NN + (n0 + r)) * 4 + (i & 3)] =
            acc[r] - mxs[r];
    } else {
#pragma unroll
      for (int r = 0; r < 4; r++)
        vg[(size_t)(b * NN + n0 + r) * DD + i] = acc[r] - mxs[r];
    }
  }
}

// ==== K2/K3: attn + ffn1 + ffn2 (+ next qkv | pool). grid (49,B), 384 ====
__global__ __launch_bounds__(384) void layer_kernel(
    const float* __restrict__ qg, const float* __restrict__ KTin,
    const float* __restrict__ vg, float* __restrict__ h,
    const float* __restrict__ wt, int f1off, int f2off,
    const float* __restrict__ tau, int qkvoff_next, float* __restrict__ qo,
    float* __restrict__ KTo, float* __restrict__ vo,
    unsigned* __restrict__ poolkey) {
  int nt = blockIdx.x, b = blockIdx.y, i0 = nt * 4;
  __shared__ float qs[4][DD];        // 2 KB
  __shared__ float hrow[4][DD];      // 2 KB (persistent x across the layer)
  __shared__ float sc[4][NN];        // 3.1 KB
  __shared__ float h1s[4][DFFV];     // 4 KB
  __shared__ float scratch[12 * 4 * DD];  // 24 KB (ored / ffn2-part alias)
  __shared__ float red[2][4];
  __shared__ float mxs[4];
  int t = threadIdx.x;
  const float4* wt4 = reinterpret_cast<const float4*>(wt);
  // ---- stage qs (own q rows) and hrow (own h rows) ----
  if (t < 128) {
    float4 val = reinterpret_cast<const float4*>(qg + (size_t)(b * NN + i0) * DD)[t];
    *reinterpret_cast<float4*>(&qs[0][0] + t * 4) = val;
  } else if (t < 256) {
    int tt = t - 128;
    float4 val = reinterpret_cast<const float4*>(h + (size_t)(b * NN + i0) * DD)[tt];
    *reinterpret_cast<float4*>(&hrow[0][0] + tt * 4) = val;
  }
  __syncthreads();
  // ---- scores: thread t = key index j; KT coalesced reads ----
  if (t < NN) {
    const float4* KT4 = reinterpret_cast<const float4*>(KTin);
    float s0 = NEGINF, s1 = NEGINF, s2 = NEGINF, s3 = NEGINF;
#pragma unroll 4
    for (int d4 = 0; d4 < DD / 4; d4++) {
      float4 kv = KT4[((size_t)b * 32 + d4) * NN + t];
      s0 = fmaxf(s0, qs[0][d4 * 4 + 0] + kv.x); s0 = fmaxf(s0, qs[0][d4 * 4 + 1] + kv.y);
      s0 = fmaxf(s0, qs[0][d4 * 4 + 2] + kv.z); s0 = fmaxf(s0, qs[0][d4 * 4 + 3] + kv.w);
      s1 = fmaxf(s1, qs[1][d4 * 4 + 0] + kv.x); s1 = fmaxf(s1, qs[1][d4 * 4 + 1] + kv.y);
      s1 = fmaxf(s1, qs[1][d4 * 4 + 2] + kv.z); s1 = fmaxf(s1, qs[1][d4 * 4 + 3] + kv.w);
      s2 = fmaxf(s2, qs[2][d4 * 4 + 0] + kv.x); s2 = fmaxf(s2, qs[2][d4 * 4 + 1] + kv.y);
      s2 = fmaxf(s2, qs[2][d4 * 4 + 2] + kv.z); s2 = fmaxf(s2, qs[2][d4 * 4 + 3] + kv.w);
      s3 = fmaxf(s3, qs[3][d4 * 4 + 0] + kv.x); s3 = fmaxf(s3, qs[3][d4 * 4 + 1] + kv.y);
      s3 = fmaxf(s3, qs[3][d4 * 4 + 2] + kv.z); s3 = fmaxf(s3, qs[3][d4 * 4 + 3] + kv.w);
    }
    sc[0][t] = s0; sc[1][t] = s1; sc[2][t] = s2; sc[3][t] = s3;
  }
  __syncthreads();
  // ---- PV: 12 j-groups x 32 d4-slots (already coalesced; unchanged) ----
  {
    int d4 = t & 31, jg = t >> 5;
    float4 o0 = {NEGINF, NEGINF, NEGINF, NEGINF};
    float4 o1 = o0, o2 = o0, o3 = o0;
#pragma unroll 4
    for (int j = jg; j < NN; j += 12) {
      float4 vv = *reinterpret_cast<const float4*>(vg + (size_t)(b * NN + j) * DD + d4 * 4);
      float c0 = sc[0][j], c1 = sc[1][j], c2 = sc[2][j], c3 = sc[3][j];
      o0.x = fmaxf(o0.x, c0 + vv.x); o0.y = fmaxf(o0.y, c0 + vv.y);
      o0.z = fmaxf(o0.z, c0 + vv.z); o0.w = fmaxf(o0.w, c0 + vv.w);
      o1.x = fmaxf(o1.x, c1 + vv.x); o1.y = fmaxf(o1.y, c1 + vv.y);
      o1.z = fmaxf(o1.z, c1 + vv.z); o1.w = fmaxf(o1.w, c1 + vv.w);
      o2.x = fmaxf(o2.x, c2 + vv.x); o2.y = fmaxf(o2.y, c2 + vv.y);
      o2.z = fmaxf(o2.z, c2 + vv.z); o2.w = fmaxf(o2.w, c2 + vv.w);
      o3.x = fmaxf(o3.x, c3 + vv.x); o3.y = fmaxf(o3.y, c3 + vv.y);
      o3.z = fmaxf(o3.z, c3 + vv.z); o3.w = fmaxf(o3.w, c3 + vv.w);
    }
    *reinterpret_cast<float4*>(&scratch[((jg * 4 + 0) << 7) + d4 * 4]) = o0;
    *reinterpret_cast<float4*>(&scratch[((jg * 4 + 1) << 7) + d4 * 4]) = o1;
    *reinterpret_cast<float4*>(&scratch[((jg * 4 + 2) << 7) + d4 * 4]) = o2;
    *reinterpret_cast<float4*>(&scratch[((jg * 4 + 3) << 7) + d4 * 4]) = o3;
  }
  __syncthreads();
  // ---- combine 12 groups, pnorm over d, tropical residual into hrow ----
  float oacc[4];
  if (t < 128) {
    int lane = t & 63, wv = t >> 6;
#pragma unroll
    for (int r = 0; r < 4; r++) {
      float m = scratch[(r << 7) + t];
#pragma unroll
      for (int g = 1; g < 12; g++) m = fmaxf(m, scratch[((g * 4 + r) << 7) + t]);
      oacc[r] = m;
      float mv = m;
#pragma unroll
      for (int mask = 32; mask >= 1; mask >>= 1) mv = fmaxf(mv, __shfl_xor(mv, mask));
      if (lane == 0) red[wv][r] = mv;
    }
  }
  __syncthreads();
  if (t < 128) {
#pragma unroll
    for (int r = 0; r < 4; r++) {
      float omax = fmaxf(red[0][r], red[1][r]);
      hrow[r][t] = fmaxf(hrow[r][t], oacc[r] - omax);
    }
  }
  __syncthreads();
  // ---- ffn1 rowmax ----
  if (t < 128) {
    int r = t >> 5, l = t & 31;
    float m = fmaxf(fmaxf(hrow[r][l], hrow[r][l + 32]), fmaxf(hrow[r][l + 64], hrow[r][l + 96]));
#pragma unroll
    for (int mask = 16; mask >= 1; mask >>= 1) m = fmaxf(m, __shfl_xor(m, mask));
    if (l == 0) mxs[r] = m;
  }
  __syncthreads();
  // ---- ffn1: coalesced f1WT reads ----
  if (t < DFFV) {
    float tv = tau[0];
    const float4* W4 = wt4 + f1off;  // [j4][o=256]
    float acc[4];
#pragma unroll
    for (int r = 0; r < 4; r++) acc[r] = NEGINF;
#pragma unroll 4
    for (int j4 = 0; j4 < DD / 4; j4++) {
      float4 w = W4[j4 * DFFV + t];
#pragma unroll
      for (int r = 0; r < 4; r++) {
        acc[r] = fmaxf(acc[r], hrow[r][j4 * 4 + 0] + w.x);
        acc[r] = fmaxf(acc[r], hrow[r][j4 * 4 + 1] + w.y);
        acc[r] = fmaxf(acc[r], hrow[r][j4 * 4 + 2] + w.z);
        acc[r] = fmaxf(acc[r], hrow[r][j4 * 4 + 3] + w.w);
      }
    }
#pragma unroll
    for (int r = 0; r < 4; r++) h1s[r][t] = fmaxf(acc[r] - mxs[r], tv);
  }
  __syncthreads();
  // ---- ffn2: coalesced f2WT reads; two DFF-halves ----
  if (t < DFFV) {
    int i = t & 127, jh = t >> 7;
    const float4* W4 = wt4 + f2off;  // [j4g 0..63][i=128]
    float acc[4];
#pragma unroll
    for (int r = 0; r < 4; r++) acc[r] = NEGINF;
#pragma unroll 4
    for (int j4 = 0; j4 < 32; j4++) {
      float4 w = W4[(jh * 32 + j4) * DD + i];
      int jb = jh * 128 + j4 * 4;
#pragma unroll
      for (int r = 0; r < 4; r++) {
        acc[r] = fmaxf(acc[r], h1s[r][jb + 0] + w.x);
        acc[r] = fmaxf(acc[r], h1s[r][jb + 1] + w.y);
        acc[r] = fmaxf(acc[r], h1s[r][jb + 2] + w.z);
        acc[r] = fmaxf(acc[r], h1s[r][jb + 3] + w.w);
      }
    }
#pragma unroll
    for (int r = 0; r < 4; r++) scratch[((jh * 4 + r) << 7) + i] = acc[r];
  }
  __syncthreads();
  float fm[4];
  if (t < 128) {
    int lane = t & 63, wv = t >> 6;
#pragma unroll
    for (int r = 0; r < 4; r++) {
      fm[r] = fmaxf(scratch[(r << 7) + t], scratch[((4 + r) << 7) + t]);
      float mv = fm[r];
#pragma unroll
      for (int mask = 32; mask >= 1; mask >>= 1) mv = fmaxf(mv, __shfl_xor(mv, mask));
      if (lane == 0) red[wv][r] = mv;
    }
  }
  __syncthreads();
  if (qkvoff_next < 0) {
    // final layer: fused global pooling over this block's 4 rows
    if (t < 128) {
      float pool = NEGINF;
#pragma unroll
      for (int r = 0; r < 4; r++) {
        float omax = fmaxf(red[0][r], red[1][r]);
        pool = fmaxf(pool, fmaxf(hrow[r][t], fm[r] - omax));
      }
      atomicMax(&poolkey[b * DD + t], keyenc(pool));
    }
    return;
  }
  // ---- ffn pnorm + residual; h hand-off; rowmax for next qkv ----
  if (t < 128) {
    int lane = t & 63, wv = t >> 6;
#pragma unroll
    for (int r = 0; r < 4; r++) {
      float omax = fmaxf(red[0][r], red[1][r]);
      float nh = fmaxf(hrow[r][t], fm[r] - omax);
      hrow[r][t] = nh;
      h[(size_t)(b * NN + i0 + r) * DD + t] = nh;
      float mv = nh;
#pragma unroll
      for (int mask = 32; mask >= 1; mask >>= 1) mv = fmaxf(mv, __shfl_xor(mv, mask));
      if (lane == 0) red[wv][r] = mv;
    }
  }
  __syncthreads();
  // ---- next-layer qkv: coalesced WT reads; k written transposed ----
  {
    int m = t >> 7, i = t & 127;
    const float4* W4 = wt4 + qkvoff_next + m * 4096;
    float acc[4], mx[4];
#pragma unroll
    for (int r = 0; r < 4; r++) {
      acc[r] = NEGINF;
      mx[r] = fmaxf(red[0][r], red[1][r]);
    }
#pragma unroll 4
    for (int j4 = 0; j4 < DD / 4; j4++) {
      float4 w = W4[j4 * DD + i];
#pragma unroll
      for (int r = 0; r < 4; r++) {
        acc[r] = fmaxf(acc[r], hrow[r][j4 * 4 + 0] + w.x);
        acc[r] = fmaxf(acc[r], hrow[r][j4 * 4 + 1] + w.y);
        acc[r] = fmaxf(acc[r], hrow[r][j4 * 4 + 2] + w.z);
        acc[r] = fmaxf(acc[r], hrow[r][j4 * 4 + 3] + w.w);
      }
    }
    if (m == 0) {
#pragma unroll
      for (int r = 0; r < 4; r++)
        qo[(size_t)(b * NN + i0 + r) * DD + i] = acc[r] - mx[r];
    } else if (m == 1) {
#pragma unroll
      for (int r = 0; r < 4; r++)
        KTo[(((size_t)b * 32 + (i >> 2)) * NN + (i0 + r)) * 4 + (i & 3)] =
            acc[r] - mx[r];
    } else {
#pragma unroll
      for (int r = 0; r < 4; r++)
        vo[(size_t)(b * NN + i0 + r) * DD + i] = acc[r] - mx[r];
    }
  }
}

// ===== K4: head from pooled keys. grid (8, B), 128 threads; hWT coalesced =
__global__ __launch_bounds__(128) void head_kernel(
    const unsigned* __restrict__ poolkey, const float* __restrict__ wt,
    const float* __restrict__ lscale, float* __restrict__ out) {
  int cb = blockIdx.x, b = blockIdx.y;
  __shared__ float pooled[DD];
  int t = threadIdx.x;
  const float4* W4 = reinterpret_cast<const float4*>(wt) + WT4_HW;  // [k4][c]
  pooled[t] = keydec(poolkey[b * DD + t]);
  __syncthreads();
  if (t < 125) {
    int c = cb * 125 + t;
    float acc = NEGINF;
#pragma unroll 4
    for (int k4 = 0; k4 < DD / 4; k4++) {
      float4 w = W4[k4 * CC + c];
      acc = fmaxf(acc, pooled[k4 * 4 + 0] + w.x);
      acc = fmaxf(acc, pooled[k4 * 4 + 1] + w.y);
      acc = fmaxf(acc, pooled[k4 * 4 + 2] + w.z);
      acc = fmaxf(acc, pooled[k4 * 4 + 3] + w.w);
    }
    out[(size_t)b * CC + c] = acc * lscale[0];
  }
}

extern "C" void kernel_launch(void* const* d_in, const int* in_sizes, int n_in,
                              void* d_out, int out_size, void* d_ws, size_t ws_size,
                              hipStream_t stream) {
  const float* x = (const float*)d_in[0];
  const float* embed_W = (const float*)d_in[1];
  const float* pos = (const float*)d_in[2];
  const float* qW0 = (const float*)d_in[3];
  const float* kW0 = (const float*)d_in[4];
  const float* vW0 = (const float*)d_in[5];
  const float* f1W0 = (const float*)d_in[6];
  const float* f2W0 = (const float*)d_in[7];
  const float* tau0 = (const float*)d_in[8];
  const float* qW1 = (const float*)d_in[9];
  const float* kW1 = (const float*)d_in[10];
  const float* vW1 = (const float*)d_in[11];
  const float* f1W1 = (const float*)d_in[12];
  const float* f2W1 = (const float*)d_in[13];
  const float* tau1 = (const float*)d_in[14];
  const float* headW = (const float*)d_in[15];
  const float* lscale = (const float*)d_in[16];
  float* out = (float*)d_out;

  float* ws = (float*)d_ws;
  size_t o = 0;
  float* h = ws + o; o += (size_t)BDIM * NN * DD;
  float* qb = ws + o; o += (size_t)BDIM * NN * DD;
  float* KT1 = ws + o; o += (size_t)BDIM * NN * DD;  // k transposed, layer0
  float* vb = ws + o; o += (size_t)BDIM * NN * DD;
  float* KT2 = ws + o; o += (size_t)BDIM * NN * DD;  // k transposed, layer1
  float* v2 = ws + o; o += (size_t)BDIM * NN * DD;
  unsigned* poolkey = (unsigned*)(ws + o); o += (size_t)BDIM * DD;
  float* wt = ws + o; o += (size_t)WT_FLOATS;

  // K0: transpose all weights into coalesced [j4][out] layout
  transpose_weights_kernel<<<dim3(WT4_TOTAL / 256 + 1), 256, 0, stream>>>(
      embed_W, qW0, kW0, vW0, qW1, kW1, vW1, f1W0, f1W1, f2W0, f2W1, headW, wt);
  // K1: embed + qkv(L0); also inits poolkey
  embed_qkv_kernel<<<dim3(49, BDIM), 384, 0, stream>>>(
      x, wt, pos, h, qb, KT1, vb, poolkey);
  // K2: attn(L0)+ffn(L0)+qkv(L1)
  layer_kernel<<<dim3(49, BDIM), 384, 0, stream>>>(
      qb, KT1, vb, h, wt, WT4_F1_0, WT4_F2_0, tau0, WT4_QKV1, qb, KT2, v2,
      poolkey);
  // K3: attn(L1)+ffn(L1) + fused global pooling
  layer_kernel<<<dim3(49, BDIM), 384, 0, stream>>>(
      qb, KT2, v2, h, wt, WT4_F1_1, WT4_F2_1, tau1, -1, nullptr, nullptr,
      nullptr, poolkey);
  // K4: head from pooled
  head_kernel<<<dim3(8, BDIM), 128, 0, stream>>>(poolkey, wt, lscale, out);
}